// Round 7
// baseline (5755.888 us; speedup 1.0000x reference)
//
#include <hip/hip_runtime.h>
#include <cstdint>
#include <math.h>

#define IN_FEAT 320
#define OUT_FEAT 2048
#define NB 8
#define KSIL 320
#define KTOT 2880          // 320 silu + 2560 spline-basis columns
#define BM1 256            // tier-1 M tile
#define BN1 256            // tier-1 N tile
#define BK1 32             // tier-1 K step (one MFMA k-depth)
#define NT1 (KTOT / BK1)   // 90 steps
#define BM 128             // tier-2 fallback tiles
#define BN 128
#define BK 32
#define LDA 40             // tier-2 fallback LDS stride
#define BN_EPS 1e-3f
#define A_OFF ((size_t)16 << 20)   // A starts 16 MB into d_ws (W lives below)

typedef __bf16 bf16;
typedef __attribute__((ext_vector_type(8))) __bf16 bf16x8;
typedef __attribute__((ext_vector_type(4))) float f32x4;

// Uniform cubic B-spline closed form == reference Cox-de Boor recursion.
__device__ __forceinline__ void bspline8(float xv, float* b) {
    float xc = (xv + 2.2f) * 2.5f;
    float cf = floorf(xc);
    int c = (int)cf;
    float t = xc - cf;
    float omt = 1.0f - t;
    float t2 = t * t, t3 = t2 * t;
    float w0 = omt * omt * omt * (1.0f / 6.0f);
    float w1 = (3.0f * t3 - 6.0f * t2 + 4.0f) * (1.0f / 6.0f);
    float w2 = (-3.0f * t3 + 3.0f * t2 + 3.0f * t + 1.0f) * (1.0f / 6.0f);
    float w3 = t3 * (1.0f / 6.0f);
    if (xc < 0.0f) { w0 = w1 = w2 = w3 = 0.0f; }
#pragma unroll
    for (int j = 0; j < 8; ++j) {
        int d = c - j;
        b[j] = (d == 3) ? w0 : (d == 2) ? w1 : (d == 1) ? w2 : (d == 0) ? w3 : 0.0f;
    }
}

__device__ __forceinline__ bf16x8 pack8(const float* f) {
    bf16x8 v;
#pragma unroll
    for (int j = 0; j < 8; ++j) v[j] = (bf16)f[j];
    return v;
}

__device__ __forceinline__ void gl2lds16(const bf16* g, bf16* l) {
    __builtin_amdgcn_global_load_lds(
        (const __attribute__((address_space(1))) void*)g,
        (__attribute__((address_space(3))) void*)l, 16, 0, 0);
}

// Fuse W = [base_weight | spline_weight*scaler] -> bf16, k-major W[o][2880].
// Vectorized: each thread produces 8 consecutive k (16-B store).
__global__ __launch_bounds__(256) void prep_w(const float* __restrict__ bw,
                                              const float* __restrict__ sw,
                                              const float* __restrict__ ss,
                                              bf16* __restrict__ W) {
    const int t = blockIdx.x * 256 + threadIdx.x;   // [0, OUT_FEAT*360)
    if (t >= OUT_FEAT * (KTOT / 8)) return;
    const int o = t / (KTOT / 8);
    const int m = t - o * (KTOT / 8);
    const int k0 = m * 8;
    float w[8];
    if (k0 < KSIL) {
        const float* p = &bw[o * IN_FEAT + k0];
#pragma unroll
        for (int u = 0; u < 8; ++u) w[u] = p[u];
    } else {
        const int i = (k0 - KSIL) >> 3;
        const float s = ss[o * IN_FEAT + i];
        const float* p = &sw[(o * IN_FEAT + i) * NB];
#pragma unroll
        for (int u = 0; u < 8; ++u) w[u] = p[u] * s;
    }
    *(bf16x8*)&W[(size_t)o * KTOT + k0] = pack8(w);
}

// Precompute A = [silu(x) | bases(x)] bf16, k-major A[row][2880].
// Vectorized: each thread handles 8 consecutive input features of one row
// (32-B read, 16-B silu store, 128-B contiguous spline store).
__global__ __launch_bounds__(256) void prep_a(const float* __restrict__ x,
                                              bf16* __restrict__ A, int total8) {
    const int t = blockIdx.x * 256 + threadIdx.x;   // [0, N*40)
    if (t >= total8) return;
    const int row = t / (IN_FEAT / 8);
    const int f0 = (t - row * (IN_FEAT / 8)) * 8;
    const float4 v0 = *(const float4*)&x[(size_t)row * IN_FEAT + f0];
    const float4 v1 = *(const float4*)&x[(size_t)row * IN_FEAT + f0 + 4];
    float xv[8] = {v0.x, v0.y, v0.z, v0.w, v1.x, v1.y, v1.z, v1.w};
    float sil[8];
#pragma unroll
    for (int u = 0; u < 8; ++u) sil[u] = xv[u] / (1.0f + __expf(-xv[u]));
    bf16* ar = A + (size_t)row * KTOT;
    *(bf16x8*)&ar[f0] = pack8(sil);
#pragma unroll
    for (int u = 0; u < 8; ++u) {
        float b[8];
        bspline8(xv[u], b);
        *(bf16x8*)&ar[KSIL + (f0 + u) * 8] = pack8(b);
    }
}

// Tier-1: pure GEMM from precomputed A (ws) and W (ws).
// 256x256 tile, BK=32, 16 waves (4Mx4N, 64x64 each), 1024 threads.
// 64 KB LDS double-buffer -> 2 blocks/CU (cross-block latency hiding).
// by = blk%8 pins each output-column strip to one XCD: its 1.47 MB W-column
// stays L2-resident. Conflict-free 4-slot XOR swizzle (extra row-bit).
__global__ __launch_bounds__(1024, 8)
void pfn_gemm_ws(const float* __restrict__ x, const bf16* __restrict__ A,
                 const bf16* __restrict__ W, const float* __restrict__ lw,
                 const float* __restrict__ gamma, const float* __restrict__ beta,
                 const float* __restrict__ mean, const float* __restrict__ var,
                 float* __restrict__ out, int N, int nbx) {
    __shared__ bf16 As[2][BM1 * BK1];   // 2 x 16 KB
    __shared__ bf16 Bs[2][BN1 * BK1];   // 2 x 16 KB  (64 KB total)

    // grid = nbx*8 exactly; by = XCD id (blk%8), bx = A-row strip.
    const int blk = blockIdx.x;
    const int by = blk & 7;
    const int bx = blk >> 3;
    if (bx >= nbx) return;

    const int row0 = bx * BM1;
    const int col0 = by * BN1;
    const int tid = threadIdx.x;
    const int wave = tid >> 6;
    const int lane = tid & 63;
    const int wr = wave >> 2;           // 0..3 -> 64-row slice
    const int wc = wave & 3;            // 0..3 -> 64-col slice
    const int l15 = lane & 15;
    const int quad = lane >> 4;

    // staging: thread owns 16-B chunk tid of each tile (1024 chunks/tile).
    // chunk q -> LDS byte q*16 = row r=q>>2, slot s=q&3; slot s of row r
    // holds k-group g = s ^ (r&3) ^ ((r>>2)&1)  (conflict-free 4-slot XOR:
    // (row parity, slot) takes 8 distinct values over r mod 8 -> 32 banks,
    // 2 lanes/bank on ds_read_b128).
    const int r0 = tid >> 2;            // 0..255
    const int s0 = tid & 3;
    const int g0 = s0 ^ (r0 & 3) ^ ((r0 >> 2) & 1);
    const bf16* a0 = A + (size_t)(row0 + r0) * KTOT + g0 * 8;
    const bf16* b0 = W + (size_t)(col0 + r0) * KTOT + g0 * 8;

    // fragment-read: k-group quad of row r sits in slot quad ^ (r&3) ^ ((r>>2)&1);
    // fragment row low 4 bits == l15 (wr*64, i*16 are 0 mod 16).
    const int sfr = quad ^ (l15 & 3) ^ ((l15 >> 2) & 1);

    f32x4 acc[4][4] = {};

    auto stage = [&](int b, int kc) {
        gl2lds16(a0 + kc, &As[b][tid * 8]);
        gl2lds16(b0 + kc, &Bs[b][tid * 8]);
    };
    auto compute = [&](int b) {
        bf16x8 af[4], bv[4];
#pragma unroll
        for (int i = 0; i < 4; ++i)
            af[i] = *(const bf16x8*)&As[b][(wr * 64 + i * 16 + l15) * BK1 + sfr * 8];
#pragma unroll
        for (int j = 0; j < 4; ++j)
            bv[j] = *(const bf16x8*)&Bs[b][(wc * 64 + j * 16 + l15) * BK1 + sfr * 8];
#pragma unroll
        for (int i = 0; i < 4; ++i)
#pragma unroll
            for (int j = 0; j < 4; ++j)
                acc[i][j] = __builtin_amdgcn_mfma_f32_16x16x32_bf16(
                    af[i], bv[j], acc[i][j], 0, 0, 0);
    };

    stage(0, 0);
    __syncthreads();                    // drain prologue stage
    int cur = 0;
    for (int tt = 0; tt < NT1; ++tt) {
        if (tt + 1 < NT1) stage(cur ^ 1, (tt + 1) * BK1);
        compute(cur);
        __syncthreads();                // drains this step's stage
        cur ^= 1;
    }

    // epilogue: + linear path, BN, ReLU, store
    const int p = by * 4 + wc;
    float sc[4], sh[4];
#pragma unroll
    for (int j = 0; j < 4; ++j) {
        const int c = j * 16 + l15;
        const float s = rsqrtf(var[c] + BN_EPS) * gamma[c];
        sc[j] = s;
        sh[j] = beta[c] - mean[c] * s;
    }
#pragma unroll
    for (int i = 0; i < 4; ++i) {
#pragma unroll
        for (int reg = 0; reg < 4; ++reg) {
            const int row = row0 + wr * 64 + i * 16 + quad * 4 + reg;
            if (row >= N) continue;
            float xq[10];
            const float* xp = &x[(size_t)row * IN_FEAT + p * 10];
#pragma unroll
            for (int q = 0; q < 10; ++q) xq[q] = xp[q];
#pragma unroll
            for (int j = 0; j < 4; ++j) {
                const int c = j * 16 + l15;
                float v = acc[i][j][reg];
#pragma unroll
                for (int q = 0; q < 10; ++q) v = fmaf(xq[q], lw[c * 10 + q], v);
                v = fmaxf(v * sc[j] + sh[j], 0.0f);
                out[((size_t)row * 32 + p) * 128 + c] = v;
            }
        }
    }
}

// ---- Tier-2/0 fallback: round-2 fused kernel (known-correct) ----
template <bool HASW>
__global__ __launch_bounds__(256)
void pfn_gemm(const float* __restrict__ x, const bf16* __restrict__ W,
              const float* __restrict__ bw, const float* __restrict__ sw,
              const float* __restrict__ ss, const float* __restrict__ lw,
              const float* __restrict__ gamma, const float* __restrict__ beta,
              const float* __restrict__ mean, const float* __restrict__ var,
              float* __restrict__ out, int N) {
    __shared__ bf16 As[BM * LDA];
    __shared__ bf16 Bs[BN * LDA];
    const int tid = threadIdx.x;
    const int row0 = blockIdx.x * BM;
    const int col0 = blockIdx.y * BN;
    const int wave = tid >> 6;
    const int lane = tid & 63;
    const int wr = wave >> 1;
    const int wc = wave & 1;
    const int l15 = lane & 15;
    const int quad = lane >> 4;
    f32x4 acc[4][4] = {};
    auto stage_b = [&](int kc) {
        const int ol = tid >> 1;
        const int k0 = (tid & 1) * 16;
        if (HASW) {
            const bf16x8* src = (const bf16x8*)&W[(size_t)(col0 + ol) * KTOT + kc + k0];
            *(bf16x8*)&Bs[ol * LDA + k0] = src[0];
            *(bf16x8*)&Bs[ol * LDA + k0 + 8] = src[1];
        } else {
            const int o = col0 + ol;
#pragma unroll
            for (int u = 0; u < 16; ++u) {
                const int gk = kc + k0 + u;
                float w;
                if (gk < KSIL) {
                    w = bw[o * IN_FEAT + gk];
                } else {
                    const int s = gk - KSIL;
                    const int i = s >> 3, j = s & 7;
                    w = sw[(o * IN_FEAT + i) * NB + j] * ss[o * IN_FEAT + i];
                }
                Bs[ol * LDA + k0 + u] = (bf16)w;
            }
        }
    };
    auto mma_step = [&]() {
        bf16x8 af[4], bv[4];
#pragma unroll
        for (int i = 0; i < 4; ++i)
            af[i] = *(const bf16x8*)&As[(wr * 64 + i * 16 + l15) * LDA + quad * 8];
#pragma unroll
        for (int j = 0; j < 4; ++j)
            bv[j] = *(const bf16x8*)&Bs[(wc * 64 + j * 16 + l15) * LDA + quad * 8];
#pragma unroll
        for (int i = 0; i < 4; ++i)
#pragma unroll
            for (int j = 0; j < 4; ++j)
                acc[i][j] = __builtin_amdgcn_mfma_f32_16x16x32_bf16(af[i], bv[j],
                                                                   acc[i][j], 0, 0, 0);
    };
    for (int kc = 0; kc < KSIL; kc += BK) {
        __syncthreads();
        stage_b(kc);
        {
            const int r = tid >> 1;
            const int k0 = (tid & 1) * 16;
            const int row = row0 + r;
            float v[16];
            if (row < N) {
                const float* xp = &x[(size_t)row * IN_FEAT + kc + k0];
#pragma unroll
                for (int u = 0; u < 16; ++u) {
                    const float xv = xp[u];
                    v[u] = xv / (1.0f + __expf(-xv));
                }
            } else {
#pragma unroll
                for (int u = 0; u < 16; ++u) v[u] = 0.0f;
            }
            *(bf16x8*)&As[r * LDA + k0] = pack8(v);
            *(bf16x8*)&As[r * LDA + k0 + 8] = pack8(v + 8);
        }
        __syncthreads();
        mma_step();
    }
    for (int kc = KSIL; kc < KTOT; kc += BK) {
        __syncthreads();
        stage_b(kc);
        {
            const int i0 = (kc - KSIL) >> 3;
#pragma unroll
            for (int s = 0; s < 2; ++s) {
                const int task = tid + s * 256;
                const int r = task >> 2;
                const int f = task & 3;
                const int row = row0 + r;
                float b[8];
                if (row < N) {
                    bspline8(x[(size_t)row * IN_FEAT + i0 + f], b);
                } else {
#pragma unroll
                    for (int j = 0; j < 8; ++j) b[j] = 0.0f;
                }
                *(bf16x8*)&As[r * LDA + f * 8] = pack8(b);
            }
        }
        __syncthreads();
        mma_step();
    }
    const int p = blockIdx.y * 2 + wc;
    float sc[4], sh[4];
#pragma unroll
    for (int j = 0; j < 4; ++j) {
        const int c = j * 16 + l15;
        const float s = rsqrtf(var[c] + BN_EPS) * gamma[c];
        sc[j] = s;
        sh[j] = beta[c] - mean[c] * s;
    }
#pragma unroll
    for (int i = 0; i < 4; ++i) {
#pragma unroll
        for (int reg = 0; reg < 4; ++reg) {
            const int row = row0 + wr * 64 + i * 16 + quad * 4 + reg;
            if (row >= N) continue;
            float xq[10];
            const float* xp = &x[(size_t)row * IN_FEAT + p * 10];
#pragma unroll
            for (int q = 0; q < 10; ++q) xq[q] = xp[q];
#pragma unroll
            for (int j = 0; j < 4; ++j) {
                const int c = j * 16 + l15;
                float v = acc[i][j][reg];
#pragma unroll
                for (int q = 0; q < 10; ++q) v = fmaf(xq[q], lw[c * 10 + q], v);
                v = fmaxf(v * sc[j] + sh[j], 0.0f);
                out[((size_t)row * 32 + p) * 128 + c] = v;
            }
        }
    }
}

// Max over the 32 points per (n, c), broadcast into out[n][p][64+c].
// Vectorized float4: 16 lanes cover c=0..63; 16 samples per block.
__global__ __launch_bounds__(256) void pfn_maxcat(float* __restrict__ out, int N) {
    const int n = blockIdx.x * 16 + (threadIdx.x >> 4);
    const int q = threadIdx.x & 15;
    if (n >= N) return;
    float* base = out + (size_t)n * 32 * 128 + q * 4;
    f32x4 m = {0.0f, 0.0f, 0.0f, 0.0f};   // post-ReLU values are >= 0
#pragma unroll
    for (int pp = 0; pp < 32; ++pp) {
        const f32x4 v = *(const f32x4*)&base[pp * 128];
        m[0] = fmaxf(m[0], v[0]);
        m[1] = fmaxf(m[1], v[1]);
        m[2] = fmaxf(m[2], v[2]);
        m[3] = fmaxf(m[3], v[3]);
    }
#pragma unroll
    for (int pp = 0; pp < 32; ++pp)
        *(f32x4*)&base[pp * 128 + 64] = m;
}

extern "C" void kernel_launch(void* const* d_in, const int* in_sizes, int n_in,
                              void* d_out, int out_size, void* d_ws, size_t ws_size,
                              hipStream_t stream) {
    const float* x     = (const float*)d_in[0];
    const float* lw    = (const float*)d_in[1];
    const float* bw    = (const float*)d_in[2];
    const float* sw    = (const float*)d_in[3];
    const float* ss    = (const float*)d_in[4];
    const float* gamma = (const float*)d_in[5];
    const float* beta  = (const float*)d_in[6];
    const float* mean  = (const float*)d_in[7];
    const float* var   = (const float*)d_in[8];
    float* out = (float*)d_out;

    const int N = in_sizes[0] / IN_FEAT;
    const int nbx = (N + BM1 - 1) / BM1;
    const size_t w_bytes = (size_t)OUT_FEAT * KTOT * sizeof(bf16);
    const size_t a_bytes = (size_t)nbx * BM1 * KTOT * sizeof(bf16);

    if (ws_size >= A_OFF + a_bytes) {
        bf16* W = (bf16*)d_ws;
        bf16* A = (bf16*)((char*)d_ws + A_OFF);
        prep_w<<<(OUT_FEAT * (KTOT / 8) + 255) / 256, 256, 0, stream>>>(bw, sw, ss, W);
        const int total8 = N * (IN_FEAT / 8);
        prep_a<<<(total8 + 255) / 256, 256, 0, stream>>>(x, A, total8);
        pfn_gemm_ws<<<nbx * 8, 1024, 0, stream>>>(x, A, W, lw, gamma, beta,
                                                  mean, var, out, N, nbx);
    } else if (ws_size >= w_bytes) {
        bf16* W = (bf16*)d_ws;
        prep_w<<<(OUT_FEAT * (KTOT / 8) + 255) / 256, 256, 0, stream>>>(bw, sw, ss, W);
        pfn_gemm<true><<<dim3((N + BM - 1) / BM, OUT_FEAT / BN), 256, 0, stream>>>(
            x, W, bw, sw, ss, lw, gamma, beta, mean, var, out, N);
    } else {
        pfn_gemm<false><<<dim3((N + BM - 1) / BM, OUT_FEAT / BN), 256, 0, stream>>>(
            x, nullptr, bw, sw, ss, lw, gamma, beta, mean, var, out, N);
    }
    pfn_maxcat<<<(N + 15) / 16, 256, 0, stream>>>(out, N);
}

// Round 9
// 1526.266 us; speedup vs baseline: 3.7712x; 3.7712x over previous
//
#include <hip/hip_runtime.h>
#include <cstdint>
#include <math.h>

#define IN_FEAT 320
#define OUT_FEAT 2048
#define NB 8
#define KSIL 320
#define KTOT 2880          // 320 silu + 2560 spline-basis columns
#define BM1 256            // tier-1 M tile
#define BN1 256            // tier-1 N tile
#define BK1 64             // tier-1 K tile
#define NT1 (KTOT / BK1)   // 45 K-tiles
#define BM 128             // tier-2 fallback tiles
#define BN 128
#define BK 32
#define LDA 40             // tier-2 fallback LDS stride
#define BN_EPS 1e-3f
#define A_OFF ((size_t)16 << 20)   // A starts 16 MB into d_ws (W lives below)

typedef __bf16 bf16;
typedef __attribute__((ext_vector_type(8))) __bf16 bf16x8;
typedef __attribute__((ext_vector_type(4))) float f32x4;

#define VMW(n) asm volatile("s_waitcnt vmcnt(" #n ")" ::: "memory")
#define BAR() __builtin_amdgcn_s_barrier()
#define LGKM0()                                            \
    do {                                                   \
        asm volatile("s_waitcnt lgkmcnt(0)" ::: "memory"); \
        __builtin_amdgcn_sched_barrier(0);                 \
    } while (0)

// Uniform cubic B-spline closed form == reference Cox-de Boor recursion.
__device__ __forceinline__ void bspline8(float xv, float* b) {
    float xc = (xv + 2.2f) * 2.5f;
    float cf = floorf(xc);
    int c = (int)cf;
    float t = xc - cf;
    float omt = 1.0f - t;
    float t2 = t * t, t3 = t2 * t;
    float w0 = omt * omt * omt * (1.0f / 6.0f);
    float w1 = (3.0f * t3 - 6.0f * t2 + 4.0f) * (1.0f / 6.0f);
    float w2 = (-3.0f * t3 + 3.0f * t2 + 3.0f * t + 1.0f) * (1.0f / 6.0f);
    float w3 = t3 * (1.0f / 6.0f);
    if (xc < 0.0f) { w0 = w1 = w2 = w3 = 0.0f; }
#pragma unroll
    for (int j = 0; j < 8; ++j) {
        int d = c - j;
        b[j] = (d == 3) ? w0 : (d == 2) ? w1 : (d == 1) ? w2 : (d == 0) ? w3 : 0.0f;
    }
}

__device__ __forceinline__ bf16x8 pack8(const float* f) {
    bf16x8 v;
#pragma unroll
    for (int j = 0; j < 8; ++j) v[j] = (bf16)f[j];
    return v;
}

__device__ __forceinline__ void gl2lds16(const bf16* g, bf16* l) {
    __builtin_amdgcn_global_load_lds(
        (const __attribute__((address_space(1))) void*)g,
        (__attribute__((address_space(3))) void*)l, 16, 0, 0);
}

// Fuse W = [base_weight | spline_weight*scaler] -> bf16, k-major W[o][2880].
__global__ __launch_bounds__(256) void prep_w(const float* __restrict__ bw,
                                              const float* __restrict__ sw,
                                              const float* __restrict__ ss,
                                              bf16* __restrict__ W) {
    const int t = blockIdx.x * 256 + threadIdx.x;   // [0, OUT_FEAT*360)
    if (t >= OUT_FEAT * (KTOT / 8)) return;
    const int o = t / (KTOT / 8);
    const int m = t - o * (KTOT / 8);
    const int k0 = m * 8;
    float w[8];
    if (k0 < KSIL) {
        const float* p = &bw[o * IN_FEAT + k0];
#pragma unroll
        for (int u = 0; u < 8; ++u) w[u] = p[u];
    } else {
        const int i = (k0 - KSIL) >> 3;
        const float s = ss[o * IN_FEAT + i];
        const float* p = &sw[(o * IN_FEAT + i) * NB];
#pragma unroll
        for (int u = 0; u < 8; ++u) w[u] = p[u] * s;
    }
    *(bf16x8*)&W[(size_t)o * KTOT + k0] = pack8(w);
}

// Precompute A = [silu(x) | bases(x)] bf16, k-major A[row][2880].
__global__ __launch_bounds__(256) void prep_a(const float* __restrict__ x,
                                              bf16* __restrict__ A, int total8) {
    const int t = blockIdx.x * 256 + threadIdx.x;   // [0, N*40)
    if (t >= total8) return;
    const int row = t / (IN_FEAT / 8);
    const int f0 = (t - row * (IN_FEAT / 8)) * 8;
    const float4 v0 = *(const float4*)&x[(size_t)row * IN_FEAT + f0];
    const float4 v1 = *(const float4*)&x[(size_t)row * IN_FEAT + f0 + 4];
    float xv[8] = {v0.x, v0.y, v0.z, v0.w, v1.x, v1.y, v1.z, v1.w};
    float sil[8];
#pragma unroll
    for (int u = 0; u < 8; ++u) sil[u] = xv[u] / (1.0f + __expf(-xv[u]));
    bf16* ar = A + (size_t)row * KTOT;
    *(bf16x8*)&ar[f0] = pack8(sil);
#pragma unroll
    for (int u = 0; u < 8; ++u) {
        float b[8];
        bspline8(xv[u], b);
        *(bf16x8*)&ar[KSIL + (f0 + u) * 8] = pack8(b);
    }
}

// Tier-1: 8-phase 256x256 GEMM (T3+T4+T5 on top of T2 swizzle).
// 8 waves (2M x 4N), per-wave 128x64 interleaved across half-tiles.
// LDS: 2 buf x {A,B} x 2 halves x (128x64) bf16 = 128 KB.
// Per K-tile: 4 phases = C-quadrants (ih,jh) in order (0,0),(0,1),(1,1),(1,0);
// each phase stages one half-tile of a future K-tile (2 x gl2lds) into the
// region whose last reader was >=1 barrier ago; ONE counted vmcnt(4)/K-tile.
__global__ __launch_bounds__(512, 2)
void pfn_gemm_ws(const float* __restrict__ x, const bf16* __restrict__ A,
                 const bf16* __restrict__ W, const float* __restrict__ lw,
                 const float* __restrict__ gamma, const float* __restrict__ beta,
                 const float* __restrict__ mean, const float* __restrict__ var,
                 float* __restrict__ out, int N, int nbx) {
    __shared__ bf16 Ah[2][2][128 * 64];   // [buf][half] 16 KB each
    __shared__ bf16 Bh[2][2][128 * 64];

    // grid = nbx*8 exactly; by = XCD id (blk%8) -> W column strip L2-pinned.
    const int blk = blockIdx.x;
    const int by = blk & 7;
    const int bx = blk >> 3;
    if (bx >= nbx) return;

    const int row0 = bx * BM1;
    const int col0 = by * BN1;
    const int tid = threadIdx.x;
    const int wave = tid >> 6;
    const int lane = tid & 63;
    const int wr = wave >> 2;           // 0..1  (M sub-slice within each half)
    const int wc = wave & 3;            // 0..3  (N sub-slice within each half)
    const int l15 = lane & 15;
    const int quad = lane >> 4;
    const int h7 = l15 & 7;

    // staging: per unit (one 128x64 half-tile) thread owns chunks tid, tid+512.
    // chunk c -> LDS byte c*16 = row r=c>>3, slot s=c&7; holds k-group
    // g = s ^ (r&7)  (8-slot XOR swizzle; uniform 8 lanes/16B-slot on reads).
    const int r0 = tid >> 3;            // 0..63 (second chunk: +64, same g)
    const int s0 = tid & 7;
    const int g0 = s0 ^ (r0 & 7);
    const bf16* aP0 = A + (size_t)(row0 + r0) * KTOT + g0 * 8;
    const bf16* aP1 = A + (size_t)(row0 + 128 + r0) * KTOT + g0 * 8;
    const bf16* bP0 = W + (size_t)(col0 + r0) * KTOT + g0 * 8;
    const bf16* bP1 = W + (size_t)(col0 + 128 + r0) * KTOT + g0 * 8;

    f32x4 acc[8][4] = {};

    auto stA = [&](int bb, int h, int tt) {
        const bf16* s = (h ? aP1 : aP0) + tt * BK1;
        bf16* d = &Ah[bb][h][0];
        gl2lds16(s, d + tid * 8);
        gl2lds16(s + (size_t)64 * KTOT, d + (tid + 512) * 8);
    };
    auto stB = [&](int bb, int h, int tt) {
        const bf16* s = (h ? bP1 : bP0) + tt * BK1;
        bf16* d = &Bh[bb][h][0];
        gl2lds16(s, d + tid * 8);
        gl2lds16(s + (size_t)64 * KTOT, d + (tid + 512) * 8);
    };
    auto ldA = [&](bf16x8 (&f)[4][2], int bb, int ih) {
        const bf16* base = &Ah[bb][ih][0];
#pragma unroll
        for (int ii = 0; ii < 4; ++ii) {
            const int rr = wr * 64 + ii * 16 + l15;
#pragma unroll
            for (int kh = 0; kh < 2; ++kh) {
                const int slot = ((kh << 2) | quad) ^ h7;
                f[ii][kh] = *(const bf16x8*)&base[rr * 64 + slot * 8];
            }
        }
    };
    auto ldB = [&](bf16x8 (&f)[2][2], int bb, int jh) {
        const bf16* base = &Bh[bb][jh][0];
#pragma unroll
        for (int jj = 0; jj < 2; ++jj) {
            const int rr = wc * 32 + jj * 16 + l15;
#pragma unroll
            for (int kh = 0; kh < 2; ++kh) {
                const int slot = ((kh << 2) | quad) ^ h7;
                f[jj][kh] = *(const bf16x8*)&base[rr * 64 + slot * 8];
            }
        }
    };
    auto MMA = [&](bf16x8 (&fa)[4][2], bf16x8 (&fb)[2][2], int i0, int j0) {
        __builtin_amdgcn_s_setprio(1);
#pragma unroll
        for (int ii = 0; ii < 4; ++ii)
#pragma unroll
            for (int jj = 0; jj < 2; ++jj)
#pragma unroll
                for (int kh = 0; kh < 2; ++kh)
                    acc[i0 + ii][j0 + jj] = __builtin_amdgcn_mfma_f32_16x16x32_bf16(
                        fa[ii][kh], fb[jj][kh], acc[i0 + ii][j0 + jj], 0, 0, 0);
        __builtin_amdgcn_s_setprio(0);
    };

    // prologue: tile0 fully + {A0,B1} of tile1  (12 loads); retire tile0.
    stA(0, 0, 0); stB(0, 0, 0); stA(0, 1, 0); stB(0, 1, 0);
    stA(1, 0, 1); stB(1, 1, 1);
    VMW(4);                               // tile0 landed; {A0(1),B1(1)} in flight
    BAR();

#pragma unroll 1
    for (int t = 0; t < NT1; ++t) {
        const int b = t & 1;
        bf16x8 af[4][2], bv0[2][2], bv1[2][2];
        // ph1: quadrant (ih0,jh0); stage A1(t+1) -> buf b^1 (freed at t-1.ph3)
        ldA(af, b, 0); ldB(bv0, b, 0);
        if (t + 1 < NT1) stA(b ^ 1, 1, t + 1);
        BAR(); LGKM0();
        MMA(af, bv0, 0, 0);
        BAR();
        // ph2: (ih0,jh1); stage B0(t+1) (freed at t-1.ph4)
        ldB(bv1, b, 1);
        if (t + 1 < NT1) stB(b ^ 1, 0, t + 1);
        BAR(); LGKM0();
        MMA(af, bv1, 0, 2);
        BAR();
        // ph3: (ih1,jh1); stage A0(t+2) -> buf b, A-half0 (last read ph1)
        ldA(af, b, 1);
        if (t + 2 < NT1) stA(b, 0, t + 2);
        BAR(); LGKM0();
        MMA(af, bv1, 4, 2);
        BAR();
        // ph4: (ih1,jh0); stage B1(t+2) -> buf b, B-half1 (last read ph2/3);
        // counted wait: retire everything of tile t+1 (leave 4 units of t+2)
        ldB(bv0, b, 0);
        if (t + 2 < NT1) stB(b, 1, t + 2);
        if (t < NT1 - 2) { VMW(4); } else { VMW(0); }
        BAR(); LGKM0();
        MMA(af, bv0, 4, 0);
        BAR();
    }

    // epilogue: + linear path, BN, ReLU, store
    // col = col0 + (j>>1)*128 + wc*32 + (j&1)*16 + l15
    const int pa = by * 4 + (wc >> 1);
    const int c0 = (wc & 1) * 32 + l15;
    const int c1 = c0 + 16;
    const float s0f = rsqrtf(var[c0] + BN_EPS) * gamma[c0];
    const float s1f = rsqrtf(var[c1] + BN_EPS) * gamma[c1];
    const float t0f = beta[c0] - mean[c0] * s0f;
    const float t1f = beta[c1] - mean[c1] * s1f;
#pragma unroll
    for (int i = 0; i < 8; ++i) {
#pragma unroll
        for (int reg = 0; reg < 4; ++reg) {
            const int row = row0 + (i >> 2) * 128 + wr * 64 + (i & 3) * 16 +
                            quad * 4 + reg;
            if (row >= N) continue;
            float xqa[10], xqb[10];
            const float* xp = &x[(size_t)row * IN_FEAT + pa * 10];
#pragma unroll
            for (int q = 0; q < 10; ++q) { xqa[q] = xp[q]; xqb[q] = xp[20 + q]; }
#pragma unroll
            for (int j = 0; j < 4; ++j) {
                const int p = pa + (j >> 1) * 2;
                const int c = (j & 1) ? c1 : c0;
                const float sc = (j & 1) ? s1f : s0f;
                const float sh = (j & 1) ? t1f : t0f;
                float v = acc[i][j][reg];
#pragma unroll
                for (int q = 0; q < 10; ++q)
                    v = fmaf((j >> 1) ? xqb[q] : xqa[q], lw[c * 10 + q], v);
                v = fmaxf(v * sc + sh, 0.0f);
                out[((size_t)row * 32 + p) * 128 + c] = v;
            }
        }
    }
}

// ---- Tier-2/0 fallback: round-2 fused kernel (known-correct) ----
template <bool HASW>
__global__ __launch_bounds__(256)
void pfn_gemm(const float* __restrict__ x, const bf16* __restrict__ W,
              const float* __restrict__ bw, const float* __restrict__ sw,
              const float* __restrict__ ss, const float* __restrict__ lw,
              const float* __restrict__ gamma, const float* __restrict__ beta,
              const float* __restrict__ mean, const float* __restrict__ var,
              float* __restrict__ out, int N) {
    __shared__ bf16 As[BM * LDA];
    __shared__ bf16 Bs[BN * LDA];
    const int tid = threadIdx.x;
    const int row0 = blockIdx.x * BM;
    const int col0 = blockIdx.y * BN;
    const int wave = tid >> 6;
    const int lane = tid & 63;
    const int wr = wave >> 1;
    const int wc = wave & 1;
    const int l15 = lane & 15;
    const int quad = lane >> 4;
    f32x4 acc[4][4] = {};
    auto stage_b = [&](int kc) {
        const int ol = tid >> 1;
        const int k0 = (tid & 1) * 16;
        if (HASW) {
            const bf16x8* src = (const bf16x8*)&W[(size_t)(col0 + ol) * KTOT + kc + k0];
            *(bf16x8*)&Bs[ol * LDA + k0] = src[0];
            *(bf16x8*)&Bs[ol * LDA + k0 + 8] = src[1];
        } else {
            const int o = col0 + ol;
#pragma unroll
            for (int u = 0; u < 16; ++u) {
                const int gk = kc + k0 + u;
                float w;
                if (gk < KSIL) {
                    w = bw[o * IN_FEAT + gk];
                } else {
                    const int s = gk - KSIL;
                    const int i = s >> 3, j = s & 7;
                    w = sw[(o * IN_FEAT + i) * NB + j] * ss[o * IN_FEAT + i];
                }
                Bs[ol * LDA + k0 + u] = (bf16)w;
            }
        }
    };
    auto mma_step = [&]() {
        bf16x8 af[4], bv[4];
#pragma unroll
        for (int i = 0; i < 4; ++i)
            af[i] = *(const bf16x8*)&As[(wr * 64 + i * 16 + l15) * LDA + quad * 8];
#pragma unroll
        for (int j = 0; j < 4; ++j)
            bv[j] = *(const bf16x8*)&Bs[(wc * 64 + j * 16 + l15) * LDA + quad * 8];
#pragma unroll
        for (int i = 0; i < 4; ++i)
#pragma unroll
            for (int j = 0; j < 4; ++j)
                acc[i][j] = __builtin_amdgcn_mfma_f32_16x16x32_bf16(af[i], bv[j],
                                                                   acc[i][j], 0, 0, 0);
    };
    for (int kc = 0; kc < KSIL; kc += BK) {
        __syncthreads();
        stage_b(kc);
        {
            const int r = tid >> 1;
            const int k0 = (tid & 1) * 16;
            const int row = row0 + r;
            float v[16];
            if (row < N) {
                const float* xp = &x[(size_t)row * IN_FEAT + kc + k0];
#pragma unroll
                for (int u = 0; u < 16; ++u) {
                    const float xv = xp[u];
                    v[u] = xv / (1.0f + __expf(-xv));
                }
            } else {
#pragma unroll
                for (int u = 0; u < 16; ++u) v[u] = 0.0f;
            }
            *(bf16x8*)&As[r * LDA + k0] = pack8(v);
            *(bf16x8*)&As[r * LDA + k0 + 8] = pack8(v + 8);
        }
        __syncthreads();
        mma_step();
    }
    for (int kc = KSIL; kc < KTOT; kc += BK) {
        __syncthreads();
        stage_b(kc);
        {
            const int i0 = (kc - KSIL) >> 3;
#pragma unroll
            for (int s = 0; s < 2; ++s) {
                const int task = tid + s * 256;
                const int r = task >> 2;
                const int f = task & 3;
                const int row = row0 + r;
                float b[8];
                if (row < N) {
                    bspline8(x[(size_t)row * IN_FEAT + i0 + f], b);
                } else {
#pragma unroll
                    for (int j = 0; j < 8; ++j) b[j] = 0.0f;
                }
                *(bf16x8*)&As[r * LDA + f * 8] = pack8(b);
            }
        }
        __syncthreads();
        mma_step();
    }
    const int p = blockIdx.y * 2 + wc;
    float sc[4], sh[4];
#pragma unroll
    for (int j = 0; j < 4; ++j) {
        const int c = j * 16 + l15;
        const float s = rsqrtf(var[c] + BN_EPS) * gamma[c];
        sc[j] = s;
        sh[j] = beta[c] - mean[c] * s;
    }
#pragma unroll
    for (int i = 0; i < 4; ++i) {
#pragma unroll
        for (int reg = 0; reg < 4; ++reg) {
            const int row = row0 + wr * 64 + i * 16 + quad * 4 + reg;
            if (row >= N) continue;
            float xq[10];
            const float* xp = &x[(size_t)row * IN_FEAT + p * 10];
#pragma unroll
            for (int q = 0; q < 10; ++q) xq[q] = xp[q];
#pragma unroll
            for (int j = 0; j < 4; ++j) {
                const int c = j * 16 + l15;
                float v = acc[i][j][reg];
#pragma unroll
                for (int q = 0; q < 10; ++q) v = fmaf(xq[q], lw[c * 10 + q], v);
                v = fmaxf(v * sc[j] + sh[j], 0.0f);
                out[((size_t)row * 32 + p) * 128 + c] = v;
            }
        }
    }
}

// Max over the 32 points per (n, c), broadcast into out[n][p][64+c].
__global__ __launch_bounds__(256) void pfn_maxcat(float* __restrict__ out, int N) {
    const int n = blockIdx.x * 16 + (threadIdx.x >> 4);
    const int q = threadIdx.x & 15;
    if (n >= N) return;
    float* base = out + (size_t)n * 32 * 128 + q * 4;
    f32x4 m = {0.0f, 0.0f, 0.0f, 0.0f};   // post-ReLU values are >= 0
#pragma unroll
    for (int pp = 0; pp < 32; ++pp) {
        const f32x4 v = *(const f32x4*)&base[pp * 128];
        m[0] = fmaxf(m[0], v[0]);
        m[1] = fmaxf(m[1], v[1]);
        m[2] = fmaxf(m[2], v[2]);
        m[3] = fmaxf(m[3], v[3]);
    }
#pragma unroll
    for (int pp = 0; pp < 32; ++pp)
        *(f32x4*)&base[pp * 128 + 64] = m;
}

extern "C" void kernel_launch(void* const* d_in, const int* in_sizes, int n_in,
                              void* d_out, int out_size, void* d_ws, size_t ws_size,
                              hipStream_t stream) {
    const float* x     = (const float*)d_in[0];
    const float* lw    = (const float*)d_in[1];
    const float* bw    = (const float*)d_in[2];
    const float* sw    = (const float*)d_in[3];
    const float* ss    = (const float*)d_in[4];
    const float* gamma = (const float*)d_in[5];
    const float* beta  = (const float*)d_in[6];
    const float* mean  = (const float*)d_in[7];
    const float* var   = (const float*)d_in[8];
    float* out = (float*)d_out;

    const int N = in_sizes[0] / IN_FEAT;
    const int nbx = (N + BM1 - 1) / BM1;
    const size_t w_bytes = (size_t)OUT_FEAT * KTOT * sizeof(bf16);
    const size_t a_bytes = (size_t)nbx * BM1 * KTOT * sizeof(bf16);

    if (ws_size >= A_OFF + a_bytes) {
        bf16* W = (bf16*)d_ws;
        bf16* A = (bf16*)((char*)d_ws + A_OFF);
        prep_w<<<(OUT_FEAT * (KTOT / 8) + 255) / 256, 256, 0, stream>>>(bw, sw, ss, W);
        const int total8 = N * (IN_FEAT / 8);
        prep_a<<<(total8 + 255) / 256, 256, 0, stream>>>(x, A, total8);
        pfn_gemm_ws<<<nbx * 8, 512, 0, stream>>>(x, A, W, lw, gamma, beta,
                                                 mean, var, out, N, nbx);
    } else if (ws_size >= w_bytes) {
        bf16* W = (bf16*)d_ws;
        prep_w<<<(OUT_FEAT * (KTOT / 8) + 255) / 256, 256, 0, stream>>>(bw, sw, ss, W);
        pfn_gemm<true><<<dim3((N + BM - 1) / BM, OUT_FEAT / BN), 256, 0, stream>>>(
            x, W, bw, sw, ss, lw, gamma, beta, mean, var, out, N);
    } else {
        pfn_gemm<false><<<dim3((N + BM - 1) / BM, OUT_FEAT / BN), 256, 0, stream>>>(
            x, nullptr, bw, sw, ss, lw, gamma, beta, mean, var, out, N);
    }
    pfn_maxcat<<<(N + 15) / 16, 256, 0, stream>>>(out, N);
}